// Round 1
// baseline (788.058 us; speedup 1.0000x reference)
//
#include <hip/hip_runtime.h>
#include <stdint.h>

// DIN attention, MI355X (gfx950).
// B=2048, T=200, H=128, H1=80, H2=40. One block per batch row b.
// Folded layer-1: din@W1 = bias1_eff(b) + keys @ Wb_eff(b)  (128x80 per-b GEMM).

#define B_SZ   2048
#define T_SZ   200
#define H_SZ   128
#define H1_SZ  80
#define H2_SZ  40
#define TPAD   208          // 13 tiles of 16
#define NMT    13
#define NEG_VAL (-1e9f)
#define SCALE_V 0.08838834764831845f   // 1/sqrt(128)

typedef __attribute__((ext_vector_type(8))) short short8v;   // 8 bf16 = 4 VGPR (MFMA A/B frag)
typedef __attribute__((ext_vector_type(4))) short short4v;
typedef __attribute__((ext_vector_type(4))) float f32x4;     // MFMA C/D frag

static __device__ __forceinline__ short f2bf(float f) {      // RNE f32->bf16
    union { float f; uint32_t u; } x; x.f = f;
    uint32_t r = x.u + 0x7fffu + ((x.u >> 16) & 1u);
    return (short)(r >> 16);
}
static __device__ __forceinline__ float bf2f(short s) {
    union { uint32_t u; float f; } x; x.u = ((uint32_t)(uint16_t)s) << 16;
    return x.f;
}

__global__ __launch_bounds__(256, 2)
void din_attn_kernel(const float* __restrict__ query, const float* __restrict__ keys,
                     const int* __restrict__ klen_arr, const float* __restrict__ W1,
                     const float* __restrict__ b1, const float* __restrict__ W2,
                     const float* __restrict__ b2, const float* __restrict__ Wf,
                     const float* __restrict__ bfp, float* __restrict__ out)
{
    // keys tile, bf16, XOR-swizzled: short index sidx = row*128+col, sidx ^= (row&7)<<3
    __shared__ __align__(16) short sK[TPAD * H_SZ];          // 53.25 KB
    __shared__ __align__(16) short sH1[4][16 * 96];          // per-wave h1 tile (K padded 80->96), 12 KB
    __shared__ float sS[TPAD];
    __shared__ float sP[TPAD];
    __shared__ float sQ[H_SZ];
    __shared__ float sBias1[H1_SZ];
    __shared__ float sB2[48];
    __shared__ float sWf[48];
    __shared__ float sRed[4], sRedL[4];
    __shared__ float sOut[2][H_SZ];

    const int tid  = threadIdx.x;
    const int b    = blockIdx.x;
    const int w    = tid >> 6;        // wave id 0..3
    const int lane = tid & 63;
    const int lo   = lane & 15;       // MFMA: col index / A-row index
    const int hi   = lane >> 4;       // MFMA: k-group / C-row group
    const int klen = klen_arr[b];
    const float bf0 = bfp[0];

    // ---------------- phase 0: stage q, b2, Wf, keys(bf16, swizzled) ----------------
    if (tid < H_SZ) sQ[tid] = query[(size_t)b * H_SZ + tid];
    if (tid >= 128 && tid < 176) { int n = tid - 128; sB2[n] = (n < H2_SZ) ? b2[n] : 0.f; }
    if (tid >= 176 && tid < 224) { int n = tid - 176; sWf[n] = (n < H2_SZ) ? Wf[n] : 0.f; }

    const float* kb = keys + (size_t)b * T_SZ * H_SZ;
    #pragma unroll
    for (int i = 0; i < 25; ++i) {                 // 25*256 = 6400 float4 = 200 rows * 128
        int idx = tid + i * 256;
        int row = idx >> 5, c4 = idx & 31;
        const float4 v = *(const float4*)(kb + row * H_SZ + c4 * 4);
        short4v s;
        s[0] = f2bf(v.x); s[1] = f2bf(v.y); s[2] = f2bf(v.z); s[3] = f2bf(v.w);
        int sidx = ((row << 7) + (c4 << 2)) ^ ((row & 7) << 3);
        *(short4v*)&sK[sidx] = s;
    }
    {   // zero pad rows 200..207
        int row = 200 + (tid >> 5), c4 = tid & 31;
        int sidx = ((row << 7) + (c4 << 2)) ^ ((row & 7) << 3);
        short4v z = {0, 0, 0, 0};
        *(short4v*)&sK[sidx] = z;
    }
    __syncthreads();   // sQ visible for fragment builds

    // ---------------- phase 1: per-b weight folding into register fragments ----------------
    // Wb_eff[k][n] = W1b[k][n] - W1c[k][n] + q[k]*W1d[k][n]   (B-frag: k = 32kt+8hi+j, n = 16nt+lo)
    short8v b1f[4][5];
    #pragma unroll
    for (int kt = 0; kt < 4; ++kt)
        #pragma unroll
        for (int nt = 0; nt < 5; ++nt) {
            short8v v;
            #pragma unroll
            for (int j = 0; j < 8; ++j) {
                int k = kt * 32 + hi * 8 + j;
                int n = nt * 16 + lo;
                float wb = W1[(128 + k) * 80 + n] - W1[(256 + k) * 80 + n]
                         + sQ[k] * W1[(384 + k) * 80 + n];
                v[j] = f2bf(wb);
            }
            b1f[kt][nt] = v;
        }
    // W2 fragments, zero-padded K 80->96, N 40->48
    short8v b2f[3][3];
    #pragma unroll
    for (int kt = 0; kt < 3; ++kt)
        #pragma unroll
        for (int nt = 0; nt < 3; ++nt) {
            short8v v;
            #pragma unroll
            for (int j = 0; j < 8; ++j) {
                int k = kt * 32 + hi * 8 + j;
                int n = nt * 16 + lo;
                float wv = (k < H1_SZ && n < H2_SZ) ? W2[k * H2_SZ + n] : 0.f;
                v[j] = f2bf(wv);
            }
            b2f[kt][nt] = v;
        }
    // bias1_eff[n] = b1[n] + sum_i q[i]*(W1a[i][n] + W1c[i][n])
    if (tid < H1_SZ) {
        float acc = b1[tid];
        #pragma unroll 8
        for (int i = 0; i < H_SZ; ++i)
            acc += sQ[i] * (W1[i * 80 + tid] + W1[(256 + i) * 80 + tid]);
        sBias1[tid] = acc;
    }
    __syncthreads();   // sBias1 ready; sK ready

    // ---------------- phase 2: per-tile MLP via MFMA -> scores ----------------
    for (int mt = w; mt < NMT; mt += 4) {
        const int t0 = mt << 4;
        f32x4 acc1[5];
        #pragma unroll
        for (int nt = 0; nt < 5; ++nt) acc1[nt] = (f32x4){0.f, 0.f, 0.f, 0.f};
        #pragma unroll
        for (int kt = 0; kt < 4; ++kt) {
            int row  = t0 + lo;
            int sidx = ((row << 7) + (kt << 5) + (hi << 3)) ^ ((row & 7) << 3);
            short8v a = *(short8v*)&sK[sidx];
            #pragma unroll
            for (int nt = 0; nt < 5; ++nt)
                acc1[nt] = __builtin_amdgcn_mfma_f32_16x16x32_bf16(a, b1f[kt][nt], acc1[nt], 0, 0, 0);
        }
        // h1 = relu(acc + bias1) -> bf16 into wave-private LDS [16][96] (cols 80..95 zero)
        short* h1p = &sH1[w][0];
        #pragma unroll
        for (int nt = 0; nt < 5; ++nt) {
            int n = nt * 16 + lo;
            float bias = sBias1[n];
            #pragma unroll
            for (int r = 0; r < 4; ++r) {
                int rl = hi * 4 + r;
                float v = fmaxf(acc1[nt][r] + bias, 0.f);
                h1p[rl * 96 + n] = f2bf(v);
            }
        }
        {
            int n = 80 + lo;
            #pragma unroll
            for (int r = 0; r < 4; ++r) h1p[(hi * 4 + r) * 96 + n] = 0;
        }
        // cross-lane LDS dependency inside the wave: drain ds_writes before frag reads
        asm volatile("s_waitcnt lgkmcnt(0)" ::: "memory");

        f32x4 acc2[3];
        #pragma unroll
        for (int nt = 0; nt < 3; ++nt) acc2[nt] = (f32x4){0.f, 0.f, 0.f, 0.f};
        #pragma unroll
        for (int kt = 0; kt < 3; ++kt) {
            short8v a2 = *(short8v*)&h1p[lo * 96 + kt * 32 + hi * 8];
            #pragma unroll
            for (int nt = 0; nt < 3; ++nt)
                acc2[nt] = __builtin_amdgcn_mfma_f32_16x16x32_bf16(a2, b2f[kt][nt], acc2[nt], 0, 0, 0);
        }
        // score[t] = sum_n relu(h2 + b2[n]) * Wf[n]  (pad cols contribute 0)
        float sc[4] = {0.f, 0.f, 0.f, 0.f};
        #pragma unroll
        for (int nt = 0; nt < 3; ++nt) {
            int n = nt * 16 + lo;
            float bb = sB2[n], wfv = sWf[n];
            #pragma unroll
            for (int r = 0; r < 4; ++r)
                sc[r] += fmaxf(acc2[nt][r] + bb, 0.f) * wfv;
        }
        #pragma unroll
        for (int m = 1; m <= 8; m <<= 1)
            #pragma unroll
            for (int r = 0; r < 4; ++r)
                sc[r] += __shfl_xor(sc[r], m, 16);
        if (lo == 0) {
            #pragma unroll
            for (int r = 0; r < 4; ++r) {
                int t = t0 + hi * 4 + r;
                sS[t] = (t < klen) ? (sc[r] + bf0) * SCALE_V : NEG_VAL;
            }
        }
    }
    __syncthreads();

    // ---------------- phase 3: softmax over 208 (masked = -1e9 -> p = 0 exactly) ----------------
    float v = (tid < TPAD) ? sS[tid] : -3.0e38f;
    #pragma unroll
    for (int m = 32; m >= 1; m >>= 1) v = fmaxf(v, __shfl_xor(v, m, 64));
    if (lane == 0) sRed[w] = v;
    __syncthreads();
    float mx = fmaxf(fmaxf(sRed[0], sRed[1]), fmaxf(sRed[2], sRed[3]));
    float pv = 0.f;
    if (tid < TPAD) { pv = __expf(sS[tid] - mx); sP[tid] = pv; }
    #pragma unroll
    for (int m = 32; m >= 1; m >>= 1) pv += __shfl_xor(pv, m, 64);
    if (lane == 0) sRedL[w] = pv;
    __syncthreads();
    const float inv_l = 1.0f / (sRedL[0] + sRedL[1] + sRedL[2] + sRedL[3]);

    // ---------------- phase 4: out[h] = sum_t p[t]*keys[t][h] / l  (keys from LDS bf16) ----------
    const int h = tid & 127, c = tid >> 7;
    float acc = 0.f;
    const int tbase = c * 104;
    #pragma unroll 8
    for (int i = 0; i < 104; ++i) {
        int t = tbase + i;
        int sidx = ((t << 7) + h) ^ ((t & 7) << 3);
        acc += sP[t] * bf2f(sK[sidx]);
    }
    sOut[c][h] = acc;
    __syncthreads();
    if (tid < 128)
        out[(size_t)b * H_SZ + tid] = (sOut[0][tid] + sOut[1][tid]) * inv_l;
}

extern "C" void kernel_launch(void* const* d_in, const int* in_sizes, int n_in,
                              void* d_out, int out_size, void* d_ws, size_t ws_size,
                              hipStream_t stream) {
    const float* query = (const float*)d_in[0];
    const float* keys  = (const float*)d_in[1];
    const int*   klen  = (const int*)d_in[2];
    const float* W1    = (const float*)d_in[3];
    const float* b1    = (const float*)d_in[4];
    const float* W2    = (const float*)d_in[5];
    const float* b2    = (const float*)d_in[6];
    const float* Wf    = (const float*)d_in[7];
    const float* bfp   = (const float*)d_in[8];
    float* outp = (float*)d_out;
    (void)in_sizes; (void)n_in; (void)out_size; (void)d_ws; (void)ws_size;
    din_attn_kernel<<<B_SZ, 256, 0, stream>>>(query, keys, klen, W1, b1, W2, b2, Wf, bfp, outp);
}

// Round 2
// 435.776 us; speedup vs baseline: 1.8084x; 1.8084x over previous
//
#include <hip/hip_runtime.h>
#include <stdint.h>

// DIN attention, MI355X (gfx950). B=2048, T=200, H=128, H1=80, H2=40.
// One block per batch row b. Folded layer-1:
//   din@W1 = bias_eff(b)[80] + keys @ Wb_eff(b)[128x80],
//   Wb_eff = (W1b - W1c) + q (.) W1d   (rowwise scale by q[k])
// Prep kernel pre-folds all b-independent weight data into d_ws in
// MFMA-fragment order so the main kernel builds fragments with coalesced
// 16B loads (R0 post-mortem: 480 scattered 4B W1 loads/thread + VGPR spill
// traffic (WRITE_SIZE=744MB) dominated at 618us).

#define B_SZ   2048
#define T_SZ   200
#define H_SZ   128
#define H1_SZ  80
#define H2_SZ  40
#define TPAD   208          // 13 tiles of 16
#define NMT    13
#define NEG_VAL (-1e9f)
#define SCALE_V 0.08838834764831845f   // 1/sqrt(128)

// d_ws layout (bytes); total 132,096 B
#define WS_BCF 0            // float[10240]  (W1b-W1c), frag order: [(kt*5+nt)*512 + l*8 + j]
#define WS_DDF 40960        // float[10240]  W1d, same order
#define WS_W2S 81920        // short[4608]   W2 bf16 frags, zero-padded K->96,N->48
#define WS_ACF 91136        // float[10240]  (W1a+W1c) transposed [n][k]

typedef __attribute__((ext_vector_type(8))) short short8v;   // 8 bf16 (MFMA A/B frag)
typedef __attribute__((ext_vector_type(4))) short short4v;
typedef __attribute__((ext_vector_type(4))) float f32x4;     // MFMA C/D frag

static __device__ __forceinline__ short f2bf(float f) {      // RNE f32->bf16
    union { float f; uint32_t u; } x; x.f = f;
    uint32_t r = x.u + 0x7fffu + ((x.u >> 16) & 1u);
    return (short)(r >> 16);
}
static __device__ __forceinline__ float bf2f(short s) {
    union { uint32_t u; float f; } x; x.u = ((uint32_t)(uint16_t)s) << 16;
    return x.f;
}

// ---------------------------------------------------------------------------
// Prep: fold b-independent weights into fragment-ordered ws buffers.
// grid = 39 blocks x 256 threads; runs in a few us, re-runs every call
// (d_ws is re-poisoned before every timed launch).
// ---------------------------------------------------------------------------
__global__ void din_prep(const float* __restrict__ W1, const float* __restrict__ W2,
                         float* __restrict__ bcf, float* __restrict__ ddf,
                         short* __restrict__ w2s, float* __restrict__ acf)
{
    const int blk = blockIdx.x, tid = threadIdx.x;
    if (blk < 20) {                       // layer-1 B-frags: fidx = kt*5+nt
        const int fidx = blk, kt = fidx / 5, nt = fidx % 5;
        #pragma unroll
        for (int e = tid; e < 512; e += 256) {
            int l = e >> 3, j = e & 7;
            int k = kt * 32 + (l >> 4) * 8 + j;
            int n = nt * 16 + (l & 15);
            bcf[fidx * 512 + e] = W1[(128 + k) * 80 + n] - W1[(256 + k) * 80 + n];
            ddf[fidx * 512 + e] = W1[(384 + k) * 80 + n];
        }
    } else if (blk < 29) {                // layer-2 B-frags: fidx = kt*3+nt
        const int fidx = blk - 20, kt = fidx / 3, nt = fidx % 3;
        #pragma unroll
        for (int e = tid; e < 512; e += 256) {
            int l = e >> 3, j = e & 7;
            int k = kt * 32 + (l >> 4) * 8 + j;
            int n = nt * 16 + (l & 15);
            float wv = (k < H1_SZ && n < H2_SZ) ? W2[k * H2_SZ + n] : 0.f;
            w2s[fidx * 512 + e] = f2bf(wv);
        }
    } else {                              // (W1a+W1c)^T for the bias dot: [n][k]
        const int base = (blk - 29) * 1024;
        #pragma unroll
        for (int i = 0; i < 4; ++i) {
            int e = base + i * 256 + tid;
            int n = e >> 7, k = e & 127;
            acf[e] = W1[k * 80 + n] + W1[(256 + k) * 80 + n];
        }
    }
}

// ---------------------------------------------------------------------------
// Main kernel: one block per b.
// ---------------------------------------------------------------------------
__global__ __launch_bounds__(256, 2)
void din_attn_kernel(const float* __restrict__ query, const float* __restrict__ keys,
                     const int* __restrict__ klen_arr, const float* __restrict__ b1,
                     const float* __restrict__ b2, const float* __restrict__ Wf,
                     const float* __restrict__ bfp, const float* __restrict__ bcf,
                     const float* __restrict__ ddf, const short* __restrict__ w2s,
                     const float* __restrict__ acf, float* __restrict__ out)
{
    // keys tile, bf16, XOR-swizzled: sidx = row*128+col (shorts), sidx ^= (row&7)<<3
    __shared__ __align__(16) short sK[TPAD * H_SZ];          // 53.25 KB
    __shared__ __align__(16) short sH1[4][16 * 96];          // per-wave h1 tile, 12 KB
    __shared__ float sS[TPAD];
    __shared__ float sP[TPAD];
    __shared__ float sBias1[H1_SZ];
    __shared__ float sB2[48];
    __shared__ float sWf[48];
    __shared__ float sRed[4], sRedL[4];
    __shared__ float sOutF[4][H_SZ];

    const int tid  = threadIdx.x;
    const int b    = blockIdx.x;
    const int w    = tid >> 6;        // wave id 0..3
    const int lane = tid & 63;
    const int lo   = lane & 15;
    const int hi   = lane >> 4;
    const int klen = klen_arr[b];
    const float bf0 = bfp[0];
    const float* qg = query + (size_t)b * H_SZ;

    // ---------------- phase 0: stage keys (bf16, swizzled), b2, Wf ----------------
    if (tid >= 128 && tid < 176) { int n = tid - 128; sB2[n] = (n < H2_SZ) ? b2[n] : 0.f; }
    if (tid >= 176 && tid < 224) { int n = tid - 176; sWf[n] = (n < H2_SZ) ? Wf[n] : 0.f; }

    const float* kb = keys + (size_t)b * T_SZ * H_SZ;
    #pragma unroll
    for (int i = 0; i < 25; ++i) {                 // 25*256 float4 = 200 rows * 128 cols
        int idx = tid + i * 256;
        int row = idx >> 5, c4 = idx & 31;
        const float4 v = *(const float4*)(kb + row * H_SZ + c4 * 4);
        short4v s;
        s[0] = f2bf(v.x); s[1] = f2bf(v.y); s[2] = f2bf(v.z); s[3] = f2bf(v.w);
        int sidx = ((row << 7) + (c4 << 2)) ^ ((row & 7) << 3);
        *(short4v*)&sK[sidx] = s;
    }
    {   // zero pad rows 200..207
        int row = 200 + (tid >> 5), c4 = tid & 31;
        int sidx = ((row << 7) + (c4 << 2)) ^ ((row & 7) << 3);
        short4v z = {0, 0, 0, 0};
        *(short4v*)&sK[sidx] = z;
    }

    // ---------------- phase 1: fragment builds — coalesced 16B loads only ----------
    // b1f[kt][nt][j] = bc + q[k]*dd, all lanes' data contiguous in frag order.
    short8v b1f[4][5];
    #pragma unroll
    for (int kt = 0; kt < 4; ++kt) {
        const float4 q0 = *(const float4*)(qg + kt * 32 + hi * 8);
        const float4 q1 = *(const float4*)(qg + kt * 32 + hi * 8 + 4);
        const float qv[8] = {q0.x, q0.y, q0.z, q0.w, q1.x, q1.y, q1.z, q1.w};
        #pragma unroll
        for (int nt = 0; nt < 5; ++nt) {
            const int base = ((kt * 5 + nt) * 64 + lane) * 8;
            const float4 c0 = *(const float4*)(bcf + base);
            const float4 c1 = *(const float4*)(bcf + base + 4);
            const float4 d0 = *(const float4*)(ddf + base);
            const float4 d1 = *(const float4*)(ddf + base + 4);
            short8v v;
            v[0] = f2bf(c0.x + qv[0] * d0.x);
            v[1] = f2bf(c0.y + qv[1] * d0.y);
            v[2] = f2bf(c0.z + qv[2] * d0.z);
            v[3] = f2bf(c0.w + qv[3] * d0.w);
            v[4] = f2bf(c1.x + qv[4] * d1.x);
            v[5] = f2bf(c1.y + qv[5] * d1.y);
            v[6] = f2bf(c1.z + qv[6] * d1.z);
            v[7] = f2bf(c1.w + qv[7] * d1.w);
            b1f[kt][nt] = v;
        }
    }
    short8v b2f[3][3];
    #pragma unroll
    for (int kt = 0; kt < 3; ++kt)
        #pragma unroll
        for (int nt = 0; nt < 3; ++nt)
            b2f[kt][nt] = *(const short8v*)(w2s + ((kt * 3 + nt) * 64 + lane) * 8);

    // bias_eff[n] = b1[n] + q . (W1a+W1c)[:,n]   (acf is [n][k], L2/L3-resident)
    if (tid < H1_SZ) {
        float acc = b1[tid];
        const float* ar = acf + tid * H_SZ;
        #pragma unroll
        for (int i = 0; i < 32; ++i) {
            const float4 wv = *(const float4*)(ar + i * 4);
            const float4 q4 = *(const float4*)(qg + i * 4);
            acc += wv.x * q4.x + wv.y * q4.y + wv.z * q4.z + wv.w * q4.w;
        }
        sBias1[tid] = acc;
    }
    __syncthreads();   // sK, sBias1, sB2, sWf all staged

    // ---------------- phase 2: per-tile MLP via MFMA -> scores ----------------
    for (int mt = w; mt < NMT; mt += 4) {
        const int t0 = mt << 4;
        f32x4 acc1[5];
        #pragma unroll
        for (int nt = 0; nt < 5; ++nt) acc1[nt] = (f32x4){0.f, 0.f, 0.f, 0.f};
        #pragma unroll
        for (int kt = 0; kt < 4; ++kt) {
            int row  = t0 + lo;
            int sidx = ((row << 7) + (kt << 5) + (hi << 3)) ^ ((row & 7) << 3);
            short8v a = *(short8v*)&sK[sidx];
            #pragma unroll
            for (int nt = 0; nt < 5; ++nt)
                acc1[nt] = __builtin_amdgcn_mfma_f32_16x16x32_bf16(a, b1f[kt][nt], acc1[nt], 0, 0, 0);
        }
        // h1 = relu(acc + bias) -> bf16 wave-private LDS [16][96] (cols 80..95 zero)
        short* h1p = &sH1[w][0];
        #pragma unroll
        for (int nt = 0; nt < 5; ++nt) {
            int n = nt * 16 + lo;
            float bias = sBias1[n];
            #pragma unroll
            for (int r = 0; r < 4; ++r) {
                int rl = hi * 4 + r;
                float v = fmaxf(acc1[nt][r] + bias, 0.f);
                h1p[rl * 96 + n] = f2bf(v);
            }
        }
        {
            int n = 80 + lo;
            #pragma unroll
            for (int r = 0; r < 4; ++r) h1p[(hi * 4 + r) * 96 + n] = 0;
        }
        // cross-lane LDS dep inside the wave: drain ds_writes before frag reads
        asm volatile("s_waitcnt lgkmcnt(0)" ::: "memory");

        f32x4 acc2[3];
        #pragma unroll
        for (int nt = 0; nt < 3; ++nt) acc2[nt] = (f32x4){0.f, 0.f, 0.f, 0.f};
        #pragma unroll
        for (int kt = 0; kt < 3; ++kt) {
            short8v a2 = *(short8v*)&h1p[lo * 96 + kt * 32 + hi * 8];
            #pragma unroll
            for (int nt = 0; nt < 3; ++nt)
                acc2[nt] = __builtin_amdgcn_mfma_f32_16x16x32_bf16(a2, b2f[kt][nt], acc2[nt], 0, 0, 0);
        }
        // score[t] = sum_n relu(h2 + b2[n]) * Wf[n]
        float sc[4] = {0.f, 0.f, 0.f, 0.f};
        #pragma unroll
        for (int nt = 0; nt < 3; ++nt) {
            int n = nt * 16 + lo;
            float bb = sB2[n], wfv = sWf[n];
            #pragma unroll
            for (int r = 0; r < 4; ++r)
                sc[r] += fmaxf(acc2[nt][r] + bb, 0.f) * wfv;
        }
        #pragma unroll
        for (int m = 1; m <= 8; m <<= 1)
            #pragma unroll
            for (int r = 0; r < 4; ++r)
                sc[r] += __shfl_xor(sc[r], m, 16);
        if (lo == 0) {
            #pragma unroll
            for (int r = 0; r < 4; ++r) {
                int t = t0 + hi * 4 + r;
                sS[t] = (t < klen) ? (sc[r] + bf0) * SCALE_V : NEG_VAL;
            }
        }
    }
    __syncthreads();

    // ---------------- phase 3: softmax over 208 (masked -> p = 0 exactly) ----------
    float v = (tid < TPAD) ? sS[tid] : -3.0e38f;
    #pragma unroll
    for (int m = 32; m >= 1; m >>= 1) v = fmaxf(v, __shfl_xor(v, m, 64));
    if (lane == 0) sRed[w] = v;
    __syncthreads();
    const float mx = fmaxf(fmaxf(sRed[0], sRed[1]), fmaxf(sRed[2], sRed[3]));
    float pv = 0.f;
    if (tid < TPAD) { pv = __expf(sS[tid] - mx); sP[tid] = pv; }
    #pragma unroll
    for (int m = 32; m >= 1; m >>= 1) pv += __shfl_xor(pv, m, 64);
    if (lane == 0) sRedL[w] = pv;
    __syncthreads();
    const float inv_l = 1.0f / (sRedL[0] + sRedL[1] + sRedL[2] + sRedL[3]);

    // ---------------- phase 4: out[h] = sum_t p[t]*keys[t][h] / l ------------------
    // thread -> (h-pair, t-slice); ds_read_b32 gives two adjacent h per read.
    {
        const int hp = (tid & 63) * 2;
        const int c  = tid >> 6;
        float a0 = 0.f, a1 = 0.f;
        #pragma unroll 4
        for (int i = 0; i < 52; ++i) {
            int t = c * 52 + i;
            int sidx = ((t << 7) + hp) ^ ((t & 7) << 3);   // even; pair stays adjacent
            uint32_t pk = *(const uint32_t*)&sK[sidx];
            float p = sP[t];
            a0 += p * bf2f((short)(pk & 0xffff));
            a1 += p * bf2f((short)(pk >> 16));
        }
        sOutF[c][hp]     = a0;
        sOutF[c][hp + 1] = a1;
    }
    __syncthreads();
    if (tid < H_SZ)
        out[(size_t)b * H_SZ + tid] =
            (sOutF[0][tid] + sOutF[1][tid] + sOutF[2][tid] + sOutF[3][tid]) * inv_l;
}

extern "C" void kernel_launch(void* const* d_in, const int* in_sizes, int n_in,
                              void* d_out, int out_size, void* d_ws, size_t ws_size,
                              hipStream_t stream) {
    const float* query = (const float*)d_in[0];
    const float* keys  = (const float*)d_in[1];
    const int*   klen  = (const int*)d_in[2];
    const float* W1    = (const float*)d_in[3];
    const float* b1    = (const float*)d_in[4];
    const float* W2    = (const float*)d_in[5];
    const float* b2    = (const float*)d_in[6];
    const float* Wf    = (const float*)d_in[7];
    const float* bfp   = (const float*)d_in[8];
    float* outp = (float*)d_out;
    (void)in_sizes; (void)n_in; (void)out_size; (void)ws_size;

    char* ws = (char*)d_ws;
    float* bcf = (float*)(ws + WS_BCF);
    float* ddf = (float*)(ws + WS_DDF);
    short* w2s = (short*)(ws + WS_W2S);
    float* acf = (float*)(ws + WS_ACF);

    din_prep<<<39, 256, 0, stream>>>(W1, W2, bcf, ddf, w2s, acf);
    din_attn_kernel<<<B_SZ, 256, 0, stream>>>(query, keys, klen, b1, b2, Wf, bfp,
                                              bcf, ddf, w2s, acf, outp);
}

// Round 3
// 356.501 us; speedup vs baseline: 2.2105x; 1.2224x over previous
//
#include <hip/hip_runtime.h>
#include <stdint.h>

// DIN attention, MI355X (gfx950). B=2048, T=200, H=128, H1=80, H2=40.
// R2 post-mortem: 116 persistent VGPRs of MFMA fragments (duplicated per wave)
// spilled to scratch (WRITE_SIZE=309MB at VGPR cap 128). This version keeps
// layer-1 fragments in LDS (read per use via ds_read_b128) and splits T across
// 2 blocks (flash-style partial softmax + merge kernel) so LDS fits 2 blocks/CU
// and staging of one block overlaps compute of the other.
//
//   din@W1 = bias_eff(b)[80] + keys @ Wb_eff(b)[128x80]
//   Wb_eff = (W1b - W1c) + q (.) W1d     (prep pre-folds b-independent parts)

#define B_SZ   2048
#define T_SZ   200
#define H_SZ   128
#define H1_SZ  80
#define H2_SZ  40
#define THALF  100          // rows per half-block
#define TPAD_H 112          // padded to 7 tiles of 16
#define NMT_H  7
#define H1LD   104          // sH1 row stride (shorts), 16B-aligned, bank-spread
#define NEG_VAL (-1e9f)
#define SCALE_V 0.08838834764831845f   // 1/sqrt(128)

// d_ws layout (bytes)
#define WS_BCF 0            // float[10240]  (W1b-W1c), frag order [(kt*5+nt)*512 + l*8 + j]
#define WS_DDF 40960        // float[10240]  W1d, same order
#define WS_W2S 81920        // short[4608]   W2 bf16 frags, zero-padded K->96,N->48
#define WS_ACF 91136        // float[10240]  (W1a+W1c) transposed [n][k]
#define WS_O   132096       // float[2048][2][128] unnormalized partial outputs
#define WS_ML  2229248      // float[2048][2][2]   (m, l) per half
// total 2,262,016 B

typedef __attribute__((ext_vector_type(8))) short short8v;   // 8 bf16 (MFMA A/B frag)
typedef __attribute__((ext_vector_type(4))) short short4v;
typedef __attribute__((ext_vector_type(4))) float f32x4;     // MFMA C/D frag

static __device__ __forceinline__ short f2bf(float f) {      // RNE f32->bf16
    union { float f; uint32_t u; } x; x.f = f;
    uint32_t r = x.u + 0x7fffu + ((x.u >> 16) & 1u);
    return (short)(r >> 16);
}
static __device__ __forceinline__ float bf2f(short s) {
    union { uint32_t u; float f; } x; x.u = ((uint32_t)(uint16_t)s) << 16;
    return x.f;
}

// ---------------------------------------------------------------------------
// Prep: fold b-independent weights into fragment-ordered ws buffers.
// ---------------------------------------------------------------------------
__global__ void din_prep(const float* __restrict__ W1, const float* __restrict__ W2,
                         float* __restrict__ bcf, float* __restrict__ ddf,
                         short* __restrict__ w2s, float* __restrict__ acf)
{
    const int blk = blockIdx.x, tid = threadIdx.x;
    if (blk < 20) {                       // layer-1 B-frags: fidx = kt*5+nt
        const int fidx = blk, kt = fidx / 5, nt = fidx % 5;
        #pragma unroll
        for (int e = tid; e < 512; e += 256) {
            int l = e >> 3, j = e & 7;
            int k = kt * 32 + (l >> 4) * 8 + j;
            int n = nt * 16 + (l & 15);
            bcf[fidx * 512 + e] = W1[(128 + k) * 80 + n] - W1[(256 + k) * 80 + n];
            ddf[fidx * 512 + e] = W1[(384 + k) * 80 + n];
        }
    } else if (blk < 29) {                // layer-2 B-frags: fidx = kt*3+nt
        const int fidx = blk - 20, kt = fidx / 3, nt = fidx % 3;
        #pragma unroll
        for (int e = tid; e < 512; e += 256) {
            int l = e >> 3, j = e & 7;
            int k = kt * 32 + (l >> 4) * 8 + j;
            int n = nt * 16 + (l & 15);
            float wv = (k < H1_SZ && n < H2_SZ) ? W2[k * H2_SZ + n] : 0.f;
            w2s[fidx * 512 + e] = f2bf(wv);
        }
    } else {                              // (W1a+W1c)^T for the bias dot: [n][k]
        const int base = (blk - 29) * 1024;
        #pragma unroll
        for (int i = 0; i < 4; ++i) {
            int e = base + i * 256 + tid;
            int n = e >> 7, k = e & 127;
            acf[e] = W1[k * 80 + n] + W1[(256 + k) * 80 + n];
        }
    }
}

// ---------------------------------------------------------------------------
// Main kernel: one block per (b, half). 256 threads. LDS ~66KB -> 2 blocks/CU.
// ---------------------------------------------------------------------------
__global__ __launch_bounds__(256, 2)
void din_attn_kernel(const float* __restrict__ query, const float* __restrict__ keys,
                     const int* __restrict__ klen_arr, const float* __restrict__ b1,
                     const float* __restrict__ b2, const float* __restrict__ Wf,
                     const float* __restrict__ bfp, const float* __restrict__ bcf,
                     const float* __restrict__ ddf, const short* __restrict__ w2s,
                     const float* __restrict__ acf, float* __restrict__ wsO,
                     float* __restrict__ wsML)
{
    __shared__ __align__(16) short sK[TPAD_H * H_SZ];        // 28 KB, XOR-swizzled bf16
    __shared__ __align__(16) short sB1F[20 * 512];           // 20 KB layer-1 B-frags (bf16)
    __shared__ __align__(16) short sH1[4][16 * H1LD];        // 13 KB per-wave h1 tiles
    __shared__ __align__(16) float sQ[H_SZ];
    __shared__ float sS[TPAD_H];
    __shared__ float sP[TPAD_H];
    __shared__ float sBias1[H1_SZ];
    __shared__ float sB2[48];
    __shared__ float sWf[48];
    __shared__ float sRed[4], sRedL[4];
    __shared__ float sOutF[4][H_SZ];

    const int tid  = threadIdx.x;
    const int b    = blockIdx.x >> 1;
    const int half = blockIdx.x & 1;
    const int w    = tid >> 6;
    const int lane = tid & 63;
    const int lo   = lane & 15;
    const int hi   = lane >> 4;
    const int klen = klen_arr[b];
    const float bf0 = bfp[0];
    const float* qg = query + (size_t)b * H_SZ;

    // ---------------- phase 0: stage q, b2, Wf, keys-half (bf16, swizzled) --------
    if (tid < H_SZ) sQ[tid] = qg[tid];
    if (tid >= 128 && tid < 176) { int n = tid - 128; sB2[n] = (n < H2_SZ) ? b2[n] : 0.f; }
    if (tid >= 176 && tid < 224) { int n = tid - 176; sWf[n] = (n < H2_SZ) ? Wf[n] : 0.f; }

    const float* kb = keys + ((size_t)b * T_SZ + half * THALF) * H_SZ;
    #pragma unroll
    for (int i = 0; i < 13; ++i) {                 // 100 rows * 32 float4 = 3200
        int idx = tid + i * 256;
        if (idx < 3200) {
            int row = idx >> 5, c4 = idx & 31;
            const float4 v = *(const float4*)(kb + row * H_SZ + c4 * 4);
            short4v s;
            s[0] = f2bf(v.x); s[1] = f2bf(v.y); s[2] = f2bf(v.z); s[3] = f2bf(v.w);
            int sidx = ((row << 7) + (c4 << 2)) ^ ((row & 7) << 3);
            *(short4v*)&sK[sidx] = s;
        }
    }
    #pragma unroll
    for (int i = 0; i < 2; ++i) {                  // zero pad rows 100..111
        int idx = tid + i * 256;
        if (idx < 384) {
            int row = THALF + (idx >> 5), c4 = idx & 31;
            int sidx = ((row << 7) + (c4 << 2)) ^ ((row & 7) << 3);
            short4v z = {0, 0, 0, 0};
            *(short4v*)&sK[sidx] = z;
        }
    }
    // layer-2 B-frags -> registers (36 VGPR persistent; only persistent frag state)
    short8v b2f[3][3];
    #pragma unroll
    for (int kt = 0; kt < 3; ++kt)
        #pragma unroll
        for (int nt = 0; nt < 3; ++nt)
            b2f[kt][nt] = *(const short8v*)(w2s + ((kt * 3 + nt) * 64 + lane) * 8);
    __syncthreads();   // sQ (+keys) visible

    // ---------------- phase 1: build layer-1 B-frags into LDS, bias_eff -----------
    // element e = fidx*512 + l*8 + j  ->  Wb_eff[k][n], k = kt*32+(l>>4)*8+j.
    // Process float4 groups g: e = 4g..4g+3 share contiguous k (k0 multiple of 4).
    #pragma unroll
    for (int i = 0; i < 10; ++i) {                 // 2560 groups / 256 threads
        int g = tid + i * 256;
        int fidx = g >> 7;
        int kt = fidx / 5;
        int l = (g >> 1) & 63, j0 = (g & 1) * 4;
        int k0 = kt * 32 + ((l >> 4) << 3) + j0;
        const float4 c = *(const float4*)(bcf + g * 4);
        const float4 d = *(const float4*)(ddf + g * 4);
        const float4 q4 = *(const float4*)(sQ + k0);
        short4v s;
        s[0] = f2bf(c.x + q4.x * d.x);
        s[1] = f2bf(c.y + q4.y * d.y);
        s[2] = f2bf(c.z + q4.z * d.z);
        s[3] = f2bf(c.w + q4.w * d.w);
        *(short4v*)&sB1F[g * 4] = s;
    }
    // bias_eff[n] = b1[n] + q . (W1a+W1c)[:,n]
    if (tid < H1_SZ) {
        float acc = b1[tid];
        const float* ar = acf + tid * H_SZ;
        #pragma unroll
        for (int i = 0; i < 32; ++i) {
            const float4 wv = *(const float4*)(ar + i * 4);
            const float4 q4 = *(const float4*)(sQ + i * 4);
            acc += wv.x * q4.x + wv.y * q4.y + wv.z * q4.z + wv.w * q4.w;
        }
        sBias1[tid] = acc;
    }
    __syncthreads();   // sB1F, sBias1 ready

    // ---------------- phase 2: per-tile MLP via MFMA -> scores ----------------
    for (int mt = w; mt < NMT_H; mt += 4) {
        const int t0 = mt << 4;
        f32x4 acc1[5];
        #pragma unroll
        for (int nt = 0; nt < 5; ++nt) acc1[nt] = (f32x4){0.f, 0.f, 0.f, 0.f};
        #pragma unroll
        for (int kt = 0; kt < 4; ++kt) {
            int row  = t0 + lo;
            int sidx = ((row << 7) + (kt << 5) + (hi << 3)) ^ ((row & 7) << 3);
            short8v a = *(short8v*)&sK[sidx];
            #pragma unroll
            for (int nt = 0; nt < 5; ++nt) {
                short8v bfr = *(short8v*)&sB1F[((kt * 5 + nt) * 64 + lane) * 8];
                acc1[nt] = __builtin_amdgcn_mfma_f32_16x16x32_bf16(a, bfr, acc1[nt], 0, 0, 0);
            }
        }
        // h1 = relu(acc + bias) -> bf16 wave-private LDS [16][H1LD] (cols 80..95 zero)
        short* h1p = &sH1[w][0];
        #pragma unroll
        for (int nt = 0; nt < 5; ++nt) {
            int n = nt * 16 + lo;
            float bias = sBias1[n];
            #pragma unroll
            for (int r = 0; r < 4; ++r) {
                int rl = hi * 4 + r;
                float v = fmaxf(acc1[nt][r] + bias, 0.f);
                h1p[rl * H1LD + n] = f2bf(v);
            }
        }
        {
            int n = 80 + lo;
            #pragma unroll
            for (int r = 0; r < 4; ++r) h1p[(hi * 4 + r) * H1LD + n] = 0;
        }
        // cross-lane LDS dep inside the wave: drain ds_writes before frag reads
        asm volatile("s_waitcnt lgkmcnt(0)" ::: "memory");

        f32x4 acc2[3];
        #pragma unroll
        for (int nt = 0; nt < 3; ++nt) acc2[nt] = (f32x4){0.f, 0.f, 0.f, 0.f};
        #pragma unroll
        for (int kt = 0; kt < 3; ++kt) {
            short8v a2 = *(short8v*)&h1p[lo * H1LD + kt * 32 + hi * 8];
            #pragma unroll
            for (int nt = 0; nt < 3; ++nt)
                acc2[nt] = __builtin_amdgcn_mfma_f32_16x16x32_bf16(a2, b2f[kt][nt], acc2[nt], 0, 0, 0);
        }
        // score[t] = sum_n relu(h2 + b2[n]) * Wf[n]
        float sc[4] = {0.f, 0.f, 0.f, 0.f};
        #pragma unroll
        for (int nt = 0; nt < 3; ++nt) {
            int n = nt * 16 + lo;
            float bb = sB2[n], wfv = sWf[n];
            #pragma unroll
            for (int r = 0; r < 4; ++r)
                sc[r] += fmaxf(acc2[nt][r] + bb, 0.f) * wfv;
        }
        #pragma unroll
        for (int m = 1; m <= 8; m <<= 1)
            #pragma unroll
            for (int r = 0; r < 4; ++r)
                sc[r] += __shfl_xor(sc[r], m, 16);
        if (lo == 0) {
            #pragma unroll
            for (int r = 0; r < 4; ++r) {
                int tl = t0 + hi * 4 + r;
                int tg = half * THALF + tl;
                bool valid = (tl < THALF) && (tg < klen);
                sS[tl] = valid ? (sc[r] + bf0) * SCALE_V : NEG_VAL;
            }
        }
    }
    __syncthreads();

    // ---------------- phase 3: partial softmax over 112 ----------------
    float v = (tid < TPAD_H) ? sS[tid] : -3.0e38f;
    #pragma unroll
    for (int m = 32; m >= 1; m >>= 1) v = fmaxf(v, __shfl_xor(v, m, 64));
    if (lane == 0) sRed[w] = v;
    __syncthreads();
    const float mx = fmaxf(fmaxf(sRed[0], sRed[1]), fmaxf(sRed[2], sRed[3]));
    float pv = 0.f;
    if (tid < TPAD_H) { pv = __expf(sS[tid] - mx); sP[tid] = pv; }
    #pragma unroll
    for (int m = 32; m >= 1; m >>= 1) pv += __shfl_xor(pv, m, 64);
    if (lane == 0) sRedL[w] = pv;
    __syncthreads();
    if (tid == 0) {
        wsML[b * 4 + half * 2 + 0] = mx;
        wsML[b * 4 + half * 2 + 1] = sRedL[0] + sRedL[1] + sRedL[2] + sRedL[3];
    }

    // ---------------- phase 4: unnormalized partial out[h] = sum_t p[t]*k[t][h] ---
    {
        const int hp = (tid & 63) * 2;
        const int c  = tid >> 6;
        float a0 = 0.f, a1 = 0.f;
        #pragma unroll 4
        for (int i = 0; i < 28; ++i) {
            int t = c * 28 + i;
            int sidx = ((t << 7) + hp) ^ ((t & 7) << 3);
            uint32_t pk = *(const uint32_t*)&sK[sidx];
            float p = sP[t];
            a0 += p * bf2f((short)(pk & 0xffff));
            a1 += p * bf2f((short)(pk >> 16));
        }
        sOutF[c][hp]     = a0;
        sOutF[c][hp + 1] = a1;
    }
    __syncthreads();
    if (tid < H_SZ)
        wsO[((size_t)b * 2 + half) * H_SZ + tid] =
            sOutF[0][tid] + sOutF[1][tid] + sOutF[2][tid] + sOutF[3][tid];
}

// ---------------------------------------------------------------------------
// Merge: out = (w0*o0 + w1*o1) / (w0*l0 + w1*l1), w_i = exp(m_i - max(m0,m1)).
// Fully-masked half: m = -1e9 -> w underflows to exactly 0 (matches reference).
// ---------------------------------------------------------------------------
__global__ void din_merge(const float* __restrict__ wsO, const float* __restrict__ wsML,
                          float* __restrict__ out)
{
    int g = blockIdx.x * 256 + threadIdx.x;       // 2048*128
    int b = g >> 7, h = g & 127;
    float m0 = wsML[b * 4 + 0], l0 = wsML[b * 4 + 1];
    float m1 = wsML[b * 4 + 2], l1 = wsML[b * 4 + 3];
    float M  = fmaxf(m0, m1);
    float w0 = __expf(m0 - M), w1 = __expf(m1 - M);
    float denom = w0 * l0 + w1 * l1;
    float o0 = wsO[((size_t)b * 2 + 0) * 128 + h];
    float o1 = wsO[((size_t)b * 2 + 1) * 128 + h];
    out[g] = (w0 * o0 + w1 * o1) / denom;
}

extern "C" void kernel_launch(void* const* d_in, const int* in_sizes, int n_in,
                              void* d_out, int out_size, void* d_ws, size_t ws_size,
                              hipStream_t stream) {
    const float* query = (const float*)d_in[0];
    const float* keys  = (const float*)d_in[1];
    const int*   klen  = (const int*)d_in[2];
    const float* W1    = (const float*)d_in[3];
    const float* b1    = (const float*)d_in[4];
    const float* W2    = (const float*)d_in[5];
    const float* b2    = (const float*)d_in[6];
    const float* Wf    = (const float*)d_in[7];
    const float* bfp   = (const float*)d_in[8];
    float* outp = (float*)d_out;
    (void)in_sizes; (void)n_in; (void)out_size; (void)ws_size;

    char* ws = (char*)d_ws;
    float* bcf  = (float*)(ws + WS_BCF);
    float* ddf  = (float*)(ws + WS_DDF);
    short* w2s  = (short*)(ws + WS_W2S);
    float* acf  = (float*)(ws + WS_ACF);
    float* wsO  = (float*)(ws + WS_O);
    float* wsML = (float*)(ws + WS_ML);

    din_prep<<<39, 256, 0, stream>>>(W1, W2, bcf, ddf, w2s, acf);
    din_attn_kernel<<<B_SZ * 2, 256, 0, stream>>>(query, keys, klen, b1, b2, Wf, bfp,
                                                  bcf, ddf, w2s, acf, wsO, wsML);
    din_merge<<<(B_SZ * H_SZ) / 256, 256, 0, stream>>>(wsO, wsML, outp);
}